// Round 12
// baseline (452.579 us; speedup 1.0000x reference)
//
#include <hip/hip_runtime.h>
#include <math.h>

#define BB  4
#define KK  16
#define MSn 4096
#define NTn 16384
#define GRIDN 16
#define NCELL (GRIDN*GRIDN*GRIDN)   // 4096 cells
#define CW   0.45f
#define CO   (-3.6f)

// Kernel 1: val[b,m] = sigmoid(conv_b + sum_k w[k] * softmax_k(logits[b,:,m]))
__global__ __launch_bounds__(256) void sgg_val_kernel(
    const float* __restrict__ logits,  // [B,K,MS]
    const float* __restrict__ w,       // [1,K,1]
    const float* __restrict__ bias,    // [1]
    float* __restrict__ val)           // [B,MS]
{
    int i = blockIdx.x * 256 + threadIdx.x;   // [0, B*MS)
    int b = i >> 12;
    int m = i & (MSn - 1);
    const float* base = logits + (size_t)b * KK * MSn + m;

    float x[KK];
    float mx = -INFINITY;
#pragma unroll
    for (int k = 0; k < KK; ++k) {
        x[k] = base[(size_t)k * MSn];
        mx = fmaxf(mx, x[k]);
    }
    float sum = 0.f;
#pragma unroll
    for (int k = 0; k < KK; ++k) {
        x[k] = expf(x[k] - mx);
        sum += x[k];
    }
    float inv = 1.0f / sum;
    float acc = bias[0];
#pragma unroll
    for (int k = 0; k < KK; ++k) {
        acc += w[k] * (x[k] * inv);
    }
    val[i] = 1.0f / (1.0f + expf(-acc));
}

// Kernel 2: counting-sort sources into 16^3 spatial cells (one block/batch).
// csrc[b][pos] = (x, y, z, bitcast(orig_index)); cellTab = start<<13 | count.
// Scatter order within a cell is non-deterministic (atomic) but the NN
// kernel's lexicographic (key, orig_index) min is order-independent.
__global__ __launch_bounds__(256) void sgg_sort_kernel(
    const float* __restrict__ spos,    // [B,3,MS]
    float4* __restrict__ csrc,         // [B,MS]
    unsigned* __restrict__ cellTab)    // [B,NCELL]
{
    __shared__ unsigned hist[NCELL];          // 16 KB
    __shared__ unsigned short cidArr[MSn];    // 8 KB
    __shared__ unsigned part[256];
    int b = blockIdx.x, t = threadIdx.x;
    const float* sp = spos + (size_t)b * 3 * MSn;

    for (int r = 0; r < NCELL / 256; ++r) hist[r * 256 + t] = 0u;
    __syncthreads();

    for (int r = 0; r < MSn / 256; ++r) {
        int i = r * 256 + t;
        float x = sp[i], y = sp[MSn + i], z = sp[2 * MSn + i];
        int cx = (int)floorf((x - CO) / CW); cx = cx < 0 ? 0 : (cx > 15 ? 15 : cx);
        int cy = (int)floorf((y - CO) / CW); cy = cy < 0 ? 0 : (cy > 15 ? 15 : cy);
        int cz = (int)floorf((z - CO) / CW); cz = cz < 0 ? 0 : (cz > 15 ? 15 : cz);
        unsigned cid = (unsigned)((cx << 8) | (cy << 4) | cz);
        cidArr[i] = (unsigned short)cid;
        atomicAdd(&hist[cid], 1u);
    }
    __syncthreads();

    unsigned cnts[NCELL / 256];
    unsigned sum = 0;
    for (int r = 0; r < 16; ++r) { cnts[r] = hist[t * 16 + r]; sum += cnts[r]; }
    part[t] = sum;
    __syncthreads();
    for (int s = 1; s < 256; s <<= 1) {
        unsigned v = (t >= s) ? part[t - s] : 0u;
        __syncthreads();
        part[t] += v;
        __syncthreads();
    }
    unsigned run = part[t] - sum;   // exclusive base of this thread's 16 bins
    for (int r = 0; r < 16; ++r) {
        int bin = t * 16 + r;
        cellTab[(size_t)b * NCELL + bin] = (run << 13) | cnts[r];
        hist[bin] = run;            // becomes the scatter cursor
        run += cnts[r];
    }
    __syncthreads();

    for (int r = 0; r < MSn / 256; ++r) {
        int i = r * 256 + t;
        unsigned cid = cidArr[i];
        unsigned pos = atomicAdd(&hist[cid], 1u);
        float x = sp[i], y = sp[MSn + i], z = sp[2 * MSn + i];
        csrc[(size_t)b * MSn + pos] = make_float4(x, y, z, __uint_as_float((unsigned)i));
    }
}

// Evaluate all sources in one cell with reference-exact arithmetic:
//   ss  = (s0*s0 + s1*s1) + s2*s2
//   dot = (t0*s0 + t1*s1) + t2*s2
//   d2  = fma(-2,dot,tt) + ss      (== (tt-(dot+dot))+ss bit-exactly)
// Lexicographic min over (monotone_uint_key(d2), orig_index) reproduces
// jnp.argmin first-occurrence semantics exactly (equal d2 -> smaller m).
__device__ __forceinline__ void scan_cell(
    int b, int cx, int cy, int cz,
    const unsigned* __restrict__ cellTab, const float4* __restrict__ csrc,
    float t0, float t1, float t2, float tt,
    unsigned& kmin, unsigned& imin, float& dminf)
{
    unsigned cid = (unsigned)((cx << 8) | (cy << 4) | cz);
    unsigned ct = cellTab[(size_t)b * NCELL + cid];
    unsigned cnt = ct & 0x1FFFu;
    const float4* p = csrc + (size_t)b * MSn + (ct >> 13);
    for (unsigned i = 0; i < cnt; ++i) {
        float4 f = p[i];
        float ss  = __fadd_rn(__fadd_rn(__fmul_rn(f.x, f.x), __fmul_rn(f.y, f.y)),
                              __fmul_rn(f.z, f.z));
        float dot = __fadd_rn(__fadd_rn(__fmul_rn(t0, f.x), __fmul_rn(t1, f.y)),
                              __fmul_rn(t2, f.z));
        float d2  = __fadd_rn(__builtin_fmaf(-2.0f, dot, tt), ss);
        unsigned mi = __float_as_uint(f.w);
        unsigned u = __float_as_uint(d2);
        unsigned k = u ^ ((unsigned)((int)u >> 31) | 0x80000000u);
        bool lt = (k < kmin) || (k == kmin && mi < imin);
        kmin  = lt ? k  : kmin;
        imin  = lt ? mi : imin;
        dminf = lt ? d2 : dminf;
    }
}

// Kernel 3: exact NN via expanding cell-cube search + table lookup.
// One thread per target; no atomics. Pruning bound: all sources outside
// the cube of cell-radius q lie beyond the nearest cube face; stop when
// dmin + 2e-3 < face_dist^2 (slack >> all f32 rounding skew, so no true
// argmin or tie can be pruned). Out-of-grid faces (clamped edge cells not
// yet enclosed) contribute INF (never prune from that side).
__global__ __launch_bounds__(256) void sgg_nn_kernel(
    const float* __restrict__ tpos,    // [B,3,NT]
    const unsigned* __restrict__ cellTab,
    const float4* __restrict__ csrc,
    const float* __restrict__ val,     // [B,MS]
    float* __restrict__ out)           // [B,NT]
{
    int n  = blockIdx.x * 256 + threadIdx.x;  // [0, B*NT)
    int b  = n >> 14;
    int ln = n & (NTn - 1);
    const float* tp = tpos + (size_t)b * 3 * NTn;
    float t0 = tp[ln], t1 = tp[NTn + ln], t2 = tp[2 * NTn + ln];
    float tt = __fadd_rn(__fadd_rn(__fmul_rn(t0, t0), __fmul_rn(t1, t1)),
                         __fmul_rn(t2, t2));

    int tcx = (int)floorf((t0 - CO) / CW); tcx = tcx < 0 ? 0 : (tcx > 15 ? 15 : tcx);
    int tcy = (int)floorf((t1 - CO) / CW); tcy = tcy < 0 ? 0 : (tcy > 15 ? 15 : tcy);
    int tcz = (int)floorf((t2 - CO) / CW); tcz = tcz < 0 ? 0 : (tcz > 15 ? 15 : tcz);

    unsigned kmin = 0xFFFFFFFFu, imin = 0xFFFFFFFFu;
    float dminf = INFINITY;

    // cube radius 1 (27 cells) — covers the common case in one pass
    for (int dz = -1; dz <= 1; ++dz) {
        int cz = tcz + dz; if ((unsigned)cz > 15u) continue;
        for (int dy = -1; dy <= 1; ++dy) {
            int cy = tcy + dy; if ((unsigned)cy > 15u) continue;
            for (int dx = -1; dx <= 1; ++dx) {
                int cx = tcx + dx; if ((unsigned)cx > 15u) continue;
                scan_cell(b, cx, cy, cz, cellTab, csrc, t0, t1, t2, tt,
                          kmin, imin, dminf);
            }
        }
    }

    // expanding shells with conservative cube-boundary bound
    for (int q = 1; q < GRIDN; ++q) {
        float db = 1e30f;
        if (tcx - q >= 1)  db = fminf(db, t0 - (CO + (float)(tcx - q) * CW));
        if (tcx + q <= 14) db = fminf(db, (CO + (float)(tcx + q + 1) * CW) - t0);
        if (tcy - q >= 1)  db = fminf(db, t1 - (CO + (float)(tcy - q) * CW));
        if (tcy + q <= 14) db = fminf(db, (CO + (float)(tcy + q + 1) * CW) - t1);
        if (tcz - q >= 1)  db = fminf(db, t2 - (CO + (float)(tcz - q) * CW));
        if (tcz + q <= 14) db = fminf(db, (CO + (float)(tcz + q + 1) * CW) - t2);
        if (db > 9e29f) break;                                   // grid fully covered
        if (__fadd_rn(dminf, 2e-3f) < __fmul_rn(db, db)) break;  // provably done

        int q1 = q + 1;   // scan shell at Chebyshev distance q1
        for (int dz = -q1; dz <= q1; ++dz) {
            int cz = tcz + dz; if ((unsigned)cz > 15u) continue;
            int az = dz < 0 ? -dz : dz;
            for (int dy = -q1; dy <= q1; ++dy) {
                int cy = tcy + dy; if ((unsigned)cy > 15u) continue;
                int ay = dy < 0 ? -dy : dy;
                int mzy = az > ay ? az : ay;
                if (mzy == q1) {
                    for (int dx = -q1; dx <= q1; ++dx) {
                        int cx = tcx + dx; if ((unsigned)cx > 15u) continue;
                        scan_cell(b, cx, cy, cz, cellTab, csrc, t0, t1, t2, tt,
                                  kmin, imin, dminf);
                    }
                } else {
                    int cx = tcx - q1;
                    if ((unsigned)cx <= 15u)
                        scan_cell(b, cx, cy, cz, cellTab, csrc, t0, t1, t2, tt,
                                  kmin, imin, dminf);
                    cx = tcx + q1;
                    if ((unsigned)cx <= 15u)
                        scan_cell(b, cx, cy, cz, cellTab, csrc, t0, t1, t2, tt,
                                  kmin, imin, dminf);
                }
            }
        }
    }

    out[n] = val[b * MSn + (int)imin];
}

extern "C" void kernel_launch(void* const* d_in, const int* in_sizes, int n_in,
                              void* d_out, int out_size, void* d_ws, size_t ws_size,
                              hipStream_t stream) {
    const float* sem  = (const float*)d_in[0];  // [4,16,4096]
    const float* spos = (const float*)d_in[1];  // [4,3,4096]
    const float* tpos = (const float*)d_in[2];  // [4,3,16384]
    const float* w    = (const float*)d_in[3];  // [1,16,1]
    const float* bias = (const float*)d_in[4];  // [1]
    float* out = (float*)d_out;                 // [4,1,16384]

    float*    val     = (float*)d_ws;                                   // 64 KB
    unsigned* cellTab = (unsigned*)((char*)d_ws + (size_t)BB * MSn * 4);        // 64 KB
    float4*   csrc    = (float4*)((char*)d_ws + (size_t)BB * MSn * 4
                                              + (size_t)BB * NCELL * 4);        // 256 KB

    sgg_sort_kernel<<<BB, 256, 0, stream>>>(spos, csrc, cellTab);
    sgg_val_kernel<<<(BB * MSn) / 256, 256, 0, stream>>>(sem, w, bias, val);
    sgg_nn_kernel<<<(BB * NTn) / 256, 256, 0, stream>>>(tpos, cellTab, csrc, val, out);
}

// Round 13
// 191.610 us; speedup vs baseline: 2.3620x; 2.3620x over previous
//
#include <hip/hip_runtime.h>
#include <math.h>

#define BB  4
#define KK  16
#define MSn 4096
#define NTn 16384
#define GRIDN 16
#define NCELL (GRIDN*GRIDN*GRIDN)   // 4096 cells
#define CW   0.45f
#define CO   (-3.6f)

// ---------------- Kernel 1: val + counters init ----------------
// val[b,m] = sigmoid(conv_b + sum_k w[k] * softmax_k(logits[b,:,m]))
__global__ __launch_bounds__(256) void sgg_val_kernel(
    const float* __restrict__ logits,  // [B,K,MS]
    const float* __restrict__ w,       // [1,K,1]
    const float* __restrict__ bias,    // [1]
    float* __restrict__ val,           // [B,MS]
    unsigned* __restrict__ counters)   // [B] spill counters (zeroed here)
{
    int i = blockIdx.x * 256 + threadIdx.x;   // [0, B*MS)
    if (i < BB) counters[i] = 0u;
    int b = i >> 12;
    int m = i & (MSn - 1);
    const float* base = logits + (size_t)b * KK * MSn + m;

    float x[KK];
    float mx = -INFINITY;
#pragma unroll
    for (int k = 0; k < KK; ++k) {
        x[k] = base[(size_t)k * MSn];
        mx = fmaxf(mx, x[k]);
    }
    float sum = 0.f;
#pragma unroll
    for (int k = 0; k < KK; ++k) {
        x[k] = expf(x[k] - mx);
        sum += x[k];
    }
    float inv = 1.0f / sum;
    float acc = bias[0];
#pragma unroll
    for (int k = 0; k < KK; ++k) {
        acc += w[k] * (x[k] * inv);
    }
    val[i] = 1.0f / (1.0f + expf(-acc));
}

// ---------------- Kernel 2: counting-sort sources into 16^3 cells ----------
// csrc[b][pos] = (x, y, z, bitcast(orig_index)); cellTab = start<<13 | count.
// Scatter order within a cell is non-deterministic (atomic) but all
// consumers use order-independent lexicographic (key, orig_index) minima.
__global__ __launch_bounds__(256) void sgg_sort_kernel(
    const float* __restrict__ spos,    // [B,3,MS]
    float4* __restrict__ csrc,         // [B,MS]
    unsigned* __restrict__ cellTab)    // [B,NCELL]
{
    __shared__ unsigned hist[NCELL];          // 16 KB
    __shared__ unsigned short cidArr[MSn];    // 8 KB
    __shared__ unsigned part[256];
    int b = blockIdx.x, t = threadIdx.x;
    const float* sp = spos + (size_t)b * 3 * MSn;

    for (int r = 0; r < NCELL / 256; ++r) hist[r * 256 + t] = 0u;
    __syncthreads();

    for (int r = 0; r < MSn / 256; ++r) {
        int i = r * 256 + t;
        float x = sp[i], y = sp[MSn + i], z = sp[2 * MSn + i];
        int cx = (int)floorf((x - CO) / CW); cx = cx < 0 ? 0 : (cx > 15 ? 15 : cx);
        int cy = (int)floorf((y - CO) / CW); cy = cy < 0 ? 0 : (cy > 15 ? 15 : cy);
        int cz = (int)floorf((z - CO) / CW); cz = cz < 0 ? 0 : (cz > 15 ? 15 : cz);
        unsigned cid = (unsigned)((cx << 8) | (cy << 4) | cz);
        cidArr[i] = (unsigned short)cid;
        atomicAdd(&hist[cid], 1u);
    }
    __syncthreads();

    unsigned cnts[NCELL / 256];
    unsigned sum = 0;
    for (int r = 0; r < 16; ++r) { cnts[r] = hist[t * 16 + r]; sum += cnts[r]; }
    part[t] = sum;
    __syncthreads();
    for (int s = 1; s < 256; s <<= 1) {
        unsigned v = (t >= s) ? part[t - s] : 0u;
        __syncthreads();
        part[t] += v;
        __syncthreads();
    }
    unsigned run = part[t] - sum;   // exclusive base of this thread's 16 bins
    for (int r = 0; r < 16; ++r) {
        int bin = t * 16 + r;
        cellTab[(size_t)b * NCELL + bin] = (run << 13) | cnts[r];
        hist[bin] = run;            // becomes the scatter cursor
        run += cnts[r];
    }
    __syncthreads();

    for (int r = 0; r < MSn / 256; ++r) {
        int i = r * 256 + t;
        unsigned cid = cidArr[i];
        unsigned pos = atomicAdd(&hist[cid], 1u);
        float x = sp[i], y = sp[MSn + i], z = sp[2 * MSn + i];
        csrc[(size_t)b * MSn + pos] = make_float4(x, y, z, __uint_as_float((unsigned)i));
    }
}

// Reference-exact per candidate:
//   ss  = (s0*s0 + s1*s1) + s2*s2
//   dot = (t0*s0 + t1*s1) + t2*s2
//   d2  = fma(-2,dot,tt) + ss      (== (tt-(dot+dot))+ss bit-exactly)
// Lexicographic min over (monotone_uint_key(d2), orig_index) == jnp.argmin.
__device__ __forceinline__ void scan_cell(
    int b, int cx, int cy, int cz,
    const unsigned* __restrict__ cellTab, const float4* __restrict__ csrc,
    float t0, float t1, float t2, float tt,
    unsigned& kmin, unsigned& imin, float& dminf)
{
    unsigned cid = (unsigned)((cx << 8) | (cy << 4) | cz);
    unsigned ct = cellTab[(size_t)b * NCELL + cid];
    unsigned cnt = ct & 0x1FFFu;
    const float4* p = csrc + (size_t)b * MSn + (ct >> 13);
    for (unsigned i = 0; i < cnt; ++i) {
        float4 f = p[i];
        float ss  = __fadd_rn(__fadd_rn(__fmul_rn(f.x, f.x), __fmul_rn(f.y, f.y)),
                              __fmul_rn(f.z, f.z));
        float dot = __fadd_rn(__fadd_rn(__fmul_rn(t0, f.x), __fmul_rn(t1, f.y)),
                              __fmul_rn(t2, f.z));
        float d2  = __fadd_rn(__builtin_fmaf(-2.0f, dot, tt), ss);
        unsigned mi = __float_as_uint(f.w);
        unsigned u = __float_as_uint(d2);
        unsigned k = u ^ ((unsigned)((int)u >> 31) | 0x80000000u);
        bool lt = (k < kmin) || (k == kmin && mi < imin);
        kmin  = lt ? k  : kmin;
        imin  = lt ? mi : imin;
        dminf = lt ? d2 : dminf;
    }
}

// ---------------- Kernel 3: radius-1 cube scan + prune-or-spill ------------
// Uniform structure (27 cells, no expanding shells -> no divergence
// amplification; R12's deep walk made 1 straggler lane cost its wave ~60K
// inst). Prune bound: sources outside the radius-1 cube lie beyond the
// nearest cube face (db >= CW = 0.45); targets with dmin^2 + 2e-3 < db^2
// (slack >> f32 rounding skew) are provably done -> write out. The rest
// (model: ~2%) spill to a per-batch list for the tail kernel.
__global__ __launch_bounds__(256) void sgg_grid_kernel(
    const float* __restrict__ tpos,    // [B,3,NT]
    const unsigned* __restrict__ cellTab,
    const float4* __restrict__ csrc,
    const float* __restrict__ val,     // [B,MS]
    float* __restrict__ out,           // [B,NT]
    unsigned* __restrict__ counters,   // [B]
    unsigned short* __restrict__ lists)// [B,NT]
{
    int n  = blockIdx.x * 256 + threadIdx.x;  // [0, B*NT)
    int b  = n >> 14;
    int ln = n & (NTn - 1);
    const float* tp = tpos + (size_t)b * 3 * NTn;
    float t0 = tp[ln], t1 = tp[NTn + ln], t2 = tp[2 * NTn + ln];
    float tt = __fadd_rn(__fadd_rn(__fmul_rn(t0, t0), __fmul_rn(t1, t1)),
                         __fmul_rn(t2, t2));

    int tcx = (int)floorf((t0 - CO) / CW); tcx = tcx < 0 ? 0 : (tcx > 15 ? 15 : tcx);
    int tcy = (int)floorf((t1 - CO) / CW); tcy = tcy < 0 ? 0 : (tcy > 15 ? 15 : tcy);
    int tcz = (int)floorf((t2 - CO) / CW); tcz = tcz < 0 ? 0 : (tcz > 15 ? 15 : tcz);

    unsigned kmin = 0xFFFFFFFFu, imin = 0xFFFFFFFFu;
    float dminf = INFINITY;

#pragma unroll
    for (int dz = -1; dz <= 1; ++dz) {
        int cz = tcz + dz; if ((unsigned)cz > 15u) continue;
#pragma unroll
        for (int dy = -1; dy <= 1; ++dy) {
            int cy = tcy + dy; if ((unsigned)cy > 15u) continue;
#pragma unroll
            for (int dx = -1; dx <= 1; ++dx) {
                int cx = tcx + dx; if ((unsigned)cx > 15u) continue;
                scan_cell(b, cx, cy, cz, cellTab, csrc, t0, t1, t2, tt,
                          kmin, imin, dminf);
            }
        }
    }

    // conservative distance to the radius-1 cube boundary (only faces with
    // grid cells beyond them bound anything; clamped edge cells inside the
    // cube already contain everything on that side)
    float db = 1e30f;
    if (tcx >= 2)  db = fminf(db, t0 - (CO + (float)(tcx - 1) * CW));
    if (tcx <= 13) db = fminf(db, (CO + (float)(tcx + 2) * CW) - t0);
    if (tcy >= 2)  db = fminf(db, t1 - (CO + (float)(tcy - 1) * CW));
    if (tcy <= 13) db = fminf(db, (CO + (float)(tcy + 2) * CW) - t1);
    if (tcz >= 2)  db = fminf(db, t2 - (CO + (float)(tcz - 1) * CW));
    if (tcz <= 13) db = fminf(db, (CO + (float)(tcz + 2) * CW) - t2);

    bool done = (kmin != 0xFFFFFFFFu) &&
                (db > 9e29f || __fadd_rn(dminf, 2e-3f) < __fmul_rn(db, db));
    if (done) {
        out[n] = val[b * MSn + (int)imin];
    } else {
        unsigned idx = atomicAdd(&counters[b], 1u);
        lists[(size_t)b * NTn + idx] = (unsigned short)ln;
    }
}

// ---------------- Kernel 4: tail — one wave per spilled target -------------
// 64 lanes scan all 4096 sources (coalesced float4 from csrc, lane handles
// m-residues), then u64 butterfly-shfl lexicographic min of
// (key<<32 | orig_index) -> exact first-occurrence argmin, no atomics.
// Deterministic: result independent of list order; each spilled target is
// written exactly once.
__global__ __launch_bounds__(256) void sgg_tail_kernel(
    const float* __restrict__ tpos,    // [B,3,NT]
    const float4* __restrict__ csrc,   // [B,MS]
    const unsigned* __restrict__ counters,
    const unsigned short* __restrict__ lists,
    const float* __restrict__ val,
    float* __restrict__ out)
{
    int lane = threadIdx.x & 63;
    int wv   = blockIdx.x * 4 + (threadIdx.x >> 6);   // global wave id, 8192 total

    for (int b = 0; b < BB; ++b) {
        unsigned cnt = counters[b];
        const float4* sq = csrc + (size_t)b * MSn;
        const float* tp = tpos + (size_t)b * 3 * NTn;
        for (unsigned i = wv; i < cnt; i += 8192) {
            int ln = lists[(size_t)b * NTn + i];
            float t0 = tp[ln], t1 = tp[NTn + ln], t2 = tp[2 * NTn + ln];
            float tt = __fadd_rn(__fadd_rn(__fmul_rn(t0, t0), __fmul_rn(t1, t1)),
                                 __fmul_rn(t2, t2));
            unsigned long long best = ~0ull;
            for (int r = 0; r < MSn / 64; ++r) {
                float4 f = sq[r * 64 + lane];         // coalesced
                float ss  = __fadd_rn(__fadd_rn(__fmul_rn(f.x, f.x), __fmul_rn(f.y, f.y)),
                                      __fmul_rn(f.z, f.z));
                float dot = __fadd_rn(__fadd_rn(__fmul_rn(t0, f.x), __fmul_rn(t1, f.y)),
                                      __fmul_rn(t2, f.z));
                float d2  = __fadd_rn(__builtin_fmaf(-2.0f, dot, tt), ss);
                unsigned u = __float_as_uint(d2);
                unsigned k = u ^ ((unsigned)((int)u >> 31) | 0x80000000u);
                unsigned long long pk =
                    ((unsigned long long)k << 32) | __float_as_uint(f.w);
                best = pk < best ? pk : best;
            }
#pragma unroll
            for (int s = 1; s < 64; s <<= 1) {
                unsigned long long o = __shfl_xor(best, s, 64);
                best = o < best ? o : best;
            }
            if (lane == 0)
                out[b * NTn + ln] = val[b * MSn + (unsigned)(best & 0xFFFFFFFFu)];
        }
    }
}

extern "C" void kernel_launch(void* const* d_in, const int* in_sizes, int n_in,
                              void* d_out, int out_size, void* d_ws, size_t ws_size,
                              hipStream_t stream) {
    const float* sem  = (const float*)d_in[0];  // [4,16,4096]
    const float* spos = (const float*)d_in[1];  // [4,3,4096]
    const float* tpos = (const float*)d_in[2];  // [4,3,16384]
    const float* w    = (const float*)d_in[3];  // [1,16,1]
    const float* bias = (const float*)d_in[4];  // [1]
    float* out = (float*)d_out;                 // [4,1,16384]

    char* p = (char*)d_ws;
    float*          val     = (float*)p;                 p += (size_t)BB * MSn * 4;    // 64 KB
    unsigned*       cellTab = (unsigned*)p;              p += (size_t)BB * NCELL * 4;  // 64 KB
    float4*         csrc    = (float4*)p;                p += (size_t)BB * MSn * 16;   // 256 KB
    unsigned short* lists   = (unsigned short*)p;        p += (size_t)BB * NTn * 2;    // 128 KB
    unsigned*       counters= (unsigned*)p;                                            // 16 B

    sgg_val_kernel<<<(BB * MSn) / 256, 256, 0, stream>>>(sem, w, bias, val, counters);
    sgg_sort_kernel<<<BB, 256, 0, stream>>>(spos, csrc, cellTab);
    sgg_grid_kernel<<<(BB * NTn) / 256, 256, 0, stream>>>(tpos, cellTab, csrc, val, out,
                                                          counters, lists);
    sgg_tail_kernel<<<2048, 256, 0, stream>>>(tpos, csrc, counters, lists, val, out);
}

// Round 14
// 149.357 us; speedup vs baseline: 3.0302x; 1.2829x over previous
//
#include <hip/hip_runtime.h>
#include <math.h>

#define BB  4
#define KK  16
#define MSn 4096
#define NTn 16384
#define GRIDN 16
#define NCELL (GRIDN*GRIDN*GRIDN)   // 4096 cells
#define CW   0.45f
#define CO   (-3.6f)

// ---------------- Kernel 1: val + counters init ----------------
__global__ __launch_bounds__(256) void sgg_val_kernel(
    const float* __restrict__ logits,  // [B,K,MS]
    const float* __restrict__ w,       // [1,K,1]
    const float* __restrict__ bias,    // [1]
    float* __restrict__ val,           // [B,MS]
    unsigned* __restrict__ counters)   // [B] spill counters (zeroed here)
{
    int i = blockIdx.x * 256 + threadIdx.x;   // [0, B*MS)
    if (i < BB) counters[i] = 0u;
    int b = i >> 12;
    int m = i & (MSn - 1);
    const float* base = logits + (size_t)b * KK * MSn + m;

    float x[KK];
    float mx = -INFINITY;
#pragma unroll
    for (int k = 0; k < KK; ++k) {
        x[k] = base[(size_t)k * MSn];
        mx = fmaxf(mx, x[k]);
    }
    float sum = 0.f;
#pragma unroll
    for (int k = 0; k < KK; ++k) {
        x[k] = expf(x[k] - mx);
        sum += x[k];
    }
    float inv = 1.0f / sum;
    float acc = bias[0];
#pragma unroll
    for (int k = 0; k < KK; ++k) {
        acc += w[k] * (x[k] * inv);
    }
    val[i] = 1.0f / (1.0f + expf(-acc));
}

// ---------------- Kernel 2: counting-sort sources into 16^3 cells ----------
// csrc[b][pos] = (x,y,z,bitcast(orig_index)); cellTab = start<<13 | count.
// cid = cx<<8 | cy<<4 | cz  -> cells with same (cx,cy) are CONTIGUOUS in z,
// so a 3-z-neighborhood is one contiguous run (used by the grid kernel).
__global__ __launch_bounds__(256) void sgg_sort_kernel(
    const float* __restrict__ spos,    // [B,3,MS]
    float4* __restrict__ csrc,         // [B,MS]
    unsigned* __restrict__ cellTab)    // [B,NCELL]
{
    __shared__ unsigned hist[NCELL];          // 16 KB
    __shared__ unsigned short cidArr[MSn];    // 8 KB
    __shared__ unsigned part[256];
    int b = blockIdx.x, t = threadIdx.x;
    const float* sp = spos + (size_t)b * 3 * MSn;

    for (int r = 0; r < NCELL / 256; ++r) hist[r * 256 + t] = 0u;
    __syncthreads();

    for (int r = 0; r < MSn / 256; ++r) {
        int i = r * 256 + t;
        float x = sp[i], y = sp[MSn + i], z = sp[2 * MSn + i];
        int cx = (int)floorf((x - CO) / CW); cx = cx < 0 ? 0 : (cx > 15 ? 15 : cx);
        int cy = (int)floorf((y - CO) / CW); cy = cy < 0 ? 0 : (cy > 15 ? 15 : cy);
        int cz = (int)floorf((z - CO) / CW); cz = cz < 0 ? 0 : (cz > 15 ? 15 : cz);
        unsigned cid = (unsigned)((cx << 8) | (cy << 4) | cz);
        cidArr[i] = (unsigned short)cid;
        atomicAdd(&hist[cid], 1u);
    }
    __syncthreads();

    unsigned cnts[NCELL / 256];
    unsigned sum = 0;
    for (int r = 0; r < 16; ++r) { cnts[r] = hist[t * 16 + r]; sum += cnts[r]; }
    part[t] = sum;
    __syncthreads();
    for (int s = 1; s < 256; s <<= 1) {
        unsigned v = (t >= s) ? part[t - s] : 0u;
        __syncthreads();
        part[t] += v;
        __syncthreads();
    }
    unsigned run = part[t] - sum;
    for (int r = 0; r < 16; ++r) {
        int bin = t * 16 + r;
        cellTab[(size_t)b * NCELL + bin] = (run << 13) | cnts[r];
        hist[bin] = run;            // scatter cursor
        run += cnts[r];
    }
    __syncthreads();

    for (int r = 0; r < MSn / 256; ++r) {
        int i = r * 256 + t;
        unsigned cid = cidArr[i];
        unsigned pos = atomicAdd(&hist[cid], 1u);
        float x = sp[i], y = sp[MSn + i], z = sp[2 * MSn + i];
        csrc[(size_t)b * MSn + pos] = make_float4(x, y, z, __uint_as_float((unsigned)i));
    }
}

// ---------------- Kernel 2b: counting-sort TARGETS by cell ------------------
// Spatial coherence for the grid kernel: a wave's 64 lanes then handle
// targets in the same/adjacent cells -> cellTab/csrc loads become
// wave-broadcast (1-2 lines vs 64) and trip counts are lane-uniform.
// tsrt[b][pos] = (t0,t1,t2, bitcast(orig_ln)) — bit-exact coord copy.
__global__ __launch_bounds__(256) void sgg_tsort_kernel(
    const float* __restrict__ tpos,    // [B,3,NT]
    float4* __restrict__ tsrt)         // [B,NT]
{
    __shared__ unsigned hist[NCELL];          // 16 KB
    __shared__ unsigned short cidArr[NTn];    // 32 KB
    __shared__ unsigned part[256];
    int b = blockIdx.x, t = threadIdx.x;
    const float* tp = tpos + (size_t)b * 3 * NTn;

    for (int r = 0; r < NCELL / 256; ++r) hist[r * 256 + t] = 0u;
    __syncthreads();

    for (int r = 0; r < NTn / 256; ++r) {
        int i = r * 256 + t;
        float x = tp[i], y = tp[NTn + i], z = tp[2 * NTn + i];
        int cx = (int)floorf((x - CO) / CW); cx = cx < 0 ? 0 : (cx > 15 ? 15 : cx);
        int cy = (int)floorf((y - CO) / CW); cy = cy < 0 ? 0 : (cy > 15 ? 15 : cy);
        int cz = (int)floorf((z - CO) / CW); cz = cz < 0 ? 0 : (cz > 15 ? 15 : cz);
        unsigned cid = (unsigned)((cx << 8) | (cy << 4) | cz);
        cidArr[i] = (unsigned short)cid;
        atomicAdd(&hist[cid], 1u);
    }
    __syncthreads();

    unsigned cnts[NCELL / 256];
    unsigned sum = 0;
    for (int r = 0; r < 16; ++r) { cnts[r] = hist[t * 16 + r]; sum += cnts[r]; }
    part[t] = sum;
    __syncthreads();
    for (int s = 1; s < 256; s <<= 1) {
        unsigned v = (t >= s) ? part[t - s] : 0u;
        __syncthreads();
        part[t] += v;
        __syncthreads();
    }
    unsigned run = part[t] - sum;
    for (int r = 0; r < 16; ++r) {
        int bin = t * 16 + r;
        hist[bin] = run;
        run += cnts[r];
    }
    __syncthreads();

    for (int r = 0; r < NTn / 256; ++r) {
        int i = r * 256 + t;
        unsigned cid = cidArr[i];
        unsigned pos = atomicAdd(&hist[cid], 1u);
        float x = tp[i], y = tp[NTn + i], z = tp[2 * NTn + i];
        tsrt[(size_t)b * NTn + pos] = make_float4(x, y, z, __uint_as_float((unsigned)i));
    }
}

// ---------------- Kernel 3: radius-1 cube scan + prune-or-spill ------------
// Sorted targets; 27-cell neighborhood flattened to 9 contiguous z-runs;
// all 18 cellTab loads hoisted into one unrolled batch (issue before wait).
// Reference-exact per candidate:
//   ss  = (s0*s0 + s1*s1) + s2*s2
//   dot = (t0*s0 + t1*s1) + t2*s2
//   d2  = fma(-2,dot,tt) + ss      (== (tt-(dot+dot))+ss bit-exactly)
// Lexicographic (monotone_key(d2), orig_m) min == jnp.argmin semantics.
// Prune: sources outside the radius-1 cube lie beyond the nearest cube
// face; dmin + 2e-3 < db^2 (slack >> f32 rounding skew) -> provably done.
__global__ __launch_bounds__(256) void sgg_grid_kernel(
    const float4* __restrict__ tsrt,   // [B,NT] sorted targets
    const unsigned* __restrict__ cellTab,
    const float4* __restrict__ csrc,
    const float* __restrict__ val,     // [B,MS]
    float* __restrict__ out,           // [B,NT]
    unsigned* __restrict__ counters,   // [B]
    unsigned short* __restrict__ lists)// [B,NT]
{
    int n  = blockIdx.x * 256 + threadIdx.x;  // [0, B*NT) sorted slot
    int b  = n >> 14;
    float4 tq = tsrt[n];                      // coalesced
    float t0 = tq.x, t1 = tq.y, t2 = tq.z;
    unsigned ln = __float_as_uint(tq.w);      // original target id
    float tt = __fadd_rn(__fadd_rn(__fmul_rn(t0, t0), __fmul_rn(t1, t1)),
                         __fmul_rn(t2, t2));

    int tcx = (int)floorf((t0 - CO) / CW); tcx = tcx < 0 ? 0 : (tcx > 15 ? 15 : tcx);
    int tcy = (int)floorf((t1 - CO) / CW); tcy = tcy < 0 ? 0 : (tcy > 15 ? 15 : tcy);
    int tcz = (int)floorf((t2 - CO) / CW); tcz = tcz < 0 ? 0 : (tcz > 15 ? 15 : tcz);
    int zlo = tcz - 1 < 0 ? 0 : tcz - 1;
    int zhi = tcz + 1 > 15 ? 15 : tcz + 1;

    const unsigned* ctab = cellTab + (size_t)b * NCELL;
    unsigned S[9], E[9];
#pragma unroll
    for (int c = 0; c < 9; ++c) {             // hoisted: 18 independent loads
        int cx = tcx + (c / 3) - 1;
        int cy = tcy + (c % 3) - 1;
        bool ok = ((unsigned)cx <= 15u) && ((unsigned)cy <= 15u);
        int sx = ok ? cx : 0, sy = ok ? cy : 0;
        unsigned c0 = ctab[(sx << 8) | (sy << 4) | zlo];
        unsigned c1 = ctab[(sx << 8) | (sy << 4) | zhi];
        S[c] = c0 >> 13;
        E[c] = ok ? ((c1 >> 13) + (c1 & 0x1FFFu)) : (c0 >> 13);
    }

    unsigned kmin = 0xFFFFFFFFu, imin = 0xFFFFFFFFu;
    float dminf = INFINITY;
    const float4* sq = csrc + (size_t)b * MSn;
#pragma unroll
    for (int c = 0; c < 9; ++c) {
        for (unsigned i = S[c]; i < E[c]; ++i) {
            float4 f = sq[i];                 // lanes same cell -> broadcast
            float ss  = __fadd_rn(__fadd_rn(__fmul_rn(f.x, f.x), __fmul_rn(f.y, f.y)),
                                  __fmul_rn(f.z, f.z));
            float dot = __fadd_rn(__fadd_rn(__fmul_rn(t0, f.x), __fmul_rn(t1, f.y)),
                                  __fmul_rn(t2, f.z));
            float d2  = __fadd_rn(__builtin_fmaf(-2.0f, dot, tt), ss);
            unsigned mi = __float_as_uint(f.w);
            unsigned u = __float_as_uint(d2);
            unsigned k = u ^ ((unsigned)((int)u >> 31) | 0x80000000u);
            bool lt = (k < kmin) || (k == kmin && mi < imin);
            kmin  = lt ? k  : kmin;
            imin  = lt ? mi : imin;
            dminf = lt ? d2 : dminf;
        }
    }

    float db = 1e30f;
    if (tcx >= 2)  db = fminf(db, t0 - (CO + (float)(tcx - 1) * CW));
    if (tcx <= 13) db = fminf(db, (CO + (float)(tcx + 2) * CW) - t0);
    if (tcy >= 2)  db = fminf(db, t1 - (CO + (float)(tcy - 1) * CW));
    if (tcy <= 13) db = fminf(db, (CO + (float)(tcy + 2) * CW) - t1);
    if (tcz >= 2)  db = fminf(db, t2 - (CO + (float)(tcz - 1) * CW));
    if (tcz <= 13) db = fminf(db, (CO + (float)(tcz + 2) * CW) - t2);

    bool done = (kmin != 0xFFFFFFFFu) &&
                (db > 9e29f || __fadd_rn(dminf, 2e-3f) < __fmul_rn(db, db));
    if (done) {
        out[b * NTn + (int)ln] = val[b * MSn + (int)imin];
    } else {
        unsigned idx = atomicAdd(&counters[b], 1u);
        lists[(size_t)b * NTn + idx] = (unsigned short)ln;
    }
}

// ---------------- Kernel 4: tail — one wave per spilled target -------------
__global__ __launch_bounds__(256) void sgg_tail_kernel(
    const float* __restrict__ tpos,    // [B,3,NT]
    const float4* __restrict__ csrc,   // [B,MS]
    const unsigned* __restrict__ counters,
    const unsigned short* __restrict__ lists,
    const float* __restrict__ val,
    float* __restrict__ out)
{
    int lane = threadIdx.x & 63;
    int wv   = blockIdx.x * 4 + (threadIdx.x >> 6);   // 8192 waves total

    for (int b = 0; b < BB; ++b) {
        unsigned cnt = counters[b];
        const float4* sq = csrc + (size_t)b * MSn;
        const float* tp = tpos + (size_t)b * 3 * NTn;
        for (unsigned i = wv; i < cnt; i += 8192) {
            int ln = lists[(size_t)b * NTn + i];
            float t0 = tp[ln], t1 = tp[NTn + ln], t2 = tp[2 * NTn + ln];
            float tt = __fadd_rn(__fadd_rn(__fmul_rn(t0, t0), __fmul_rn(t1, t1)),
                                 __fmul_rn(t2, t2));
            unsigned long long best = ~0ull;
            for (int r = 0; r < MSn / 64; ++r) {
                float4 f = sq[r * 64 + lane];         // coalesced
                float ss  = __fadd_rn(__fadd_rn(__fmul_rn(f.x, f.x), __fmul_rn(f.y, f.y)),
                                      __fmul_rn(f.z, f.z));
                float dot = __fadd_rn(__fadd_rn(__fmul_rn(t0, f.x), __fmul_rn(t1, f.y)),
                                      __fmul_rn(t2, f.z));
                float d2  = __fadd_rn(__builtin_fmaf(-2.0f, dot, tt), ss);
                unsigned u = __float_as_uint(d2);
                unsigned k = u ^ ((unsigned)((int)u >> 31) | 0x80000000u);
                unsigned long long pk =
                    ((unsigned long long)k << 32) | __float_as_uint(f.w);
                best = pk < best ? pk : best;
            }
#pragma unroll
            for (int s = 1; s < 64; s <<= 1) {
                unsigned long long o = __shfl_xor(best, s, 64);
                best = o < best ? o : best;
            }
            if (lane == 0)
                out[b * NTn + ln] = val[b * MSn + (unsigned)(best & 0xFFFFFFFFu)];
        }
    }
}

extern "C" void kernel_launch(void* const* d_in, const int* in_sizes, int n_in,
                              void* d_out, int out_size, void* d_ws, size_t ws_size,
                              hipStream_t stream) {
    const float* sem  = (const float*)d_in[0];  // [4,16,4096]
    const float* spos = (const float*)d_in[1];  // [4,3,4096]
    const float* tpos = (const float*)d_in[2];  // [4,3,16384]
    const float* w    = (const float*)d_in[3];  // [1,16,1]
    const float* bias = (const float*)d_in[4];  // [1]
    float* out = (float*)d_out;                 // [4,1,16384]

    char* p = (char*)d_ws;
    float*          val     = (float*)p;          p += (size_t)BB * MSn * 4;    // 64 KB
    unsigned*       cellTab = (unsigned*)p;       p += (size_t)BB * NCELL * 4;  // 64 KB
    float4*         csrc    = (float4*)p;         p += (size_t)BB * MSn * 16;   // 256 KB
    float4*         tsrt    = (float4*)p;         p += (size_t)BB * NTn * 16;   // 1 MB
    unsigned short* lists   = (unsigned short*)p; p += (size_t)BB * NTn * 2;    // 128 KB
    unsigned*       counters= (unsigned*)p;                                     // 16 B

    sgg_val_kernel<<<(BB * MSn) / 256, 256, 0, stream>>>(sem, w, bias, val, counters);
    sgg_sort_kernel<<<BB, 256, 0, stream>>>(spos, csrc, cellTab);
    sgg_tsort_kernel<<<BB, 256, 0, stream>>>(tpos, tsrt);
    sgg_grid_kernel<<<(BB * NTn) / 256, 256, 0, stream>>>(tsrt, cellTab, csrc, val, out,
                                                          counters, lists);
    sgg_tail_kernel<<<2048, 256, 0, stream>>>(tpos, csrc, counters, lists, val, out);
}